// Round 9
// baseline (406.474 us; speedup 1.0000x reference)
//
#include <hip/hip_runtime.h>

#define COLS 16384
#define TPB  512
#define CHUNK 8                                   // f32 elems per chunk
#define CPR  (COLS / CHUNK)                       // 2048 chunks per row
#define CPT  (CPR / TPB)                          // 4 chunks per thread
#define NW   (TPB / 64)                           // 8 waves

typedef float f4 __attribute__((ext_vector_type(4)));

__global__ __launch_bounds__(TPB) void revcumsum_rows(const float* __restrict__ x,
                                                      float* __restrict__ out) {
    // Register-resident row; LDS = 4x8 wave totals. 8 waves/block -> 4 blocks/CU.
    __shared__ float s_wt[CPT][NW];

    const int t    = threadIdx.x;
    const int lane = t & 63;
    const int w    = t >> 6;
    const long long row = blockIdx.x;
    const f4* __restrict__ rowp4 = reinterpret_cast<const f4*>(x + row * (long long)COLS);
    f4* __restrict__       outp4 = reinterpret_cast<f4*>(out + row * (long long)COLS);

    // ---- Load 4 chunks (c_k = k*TPB + t) nontemporally into regs; chunk sums.
    f4 a[CPT], b[CPT];
    float v[CPT];
    #pragma unroll
    for (int k = 0; k < CPT; ++k) {
        const int c = k * TPB + t;
        a[k] = __builtin_nontemporal_load(rowp4 + 2 * c);
        b[k] = __builtin_nontemporal_load(rowp4 + 2 * c + 1);
        v[k] = ((a[k].x + a[k].y) + (a[k].z + a[k].w))
             + ((b[k].x + b[k].y) + (b[k].z + b[k].w));
    }

    // ---- 4 wave-level inclusive SUFFIX scans over thread index (one shuffle loop).
    float s[CPT];
    #pragma unroll
    for (int k = 0; k < CPT; ++k) s[k] = v[k];
    #pragma unroll
    for (int d = 1; d < 64; d <<= 1) {
        float o[CPT];
        #pragma unroll
        for (int k = 0; k < CPT; ++k) o[k] = __shfl_down(s[k], d);
        if (lane + d < 64) {
            #pragma unroll
            for (int k = 0; k < CPT; ++k) s[k] += o[k];
        }
    }
    if (lane == 0) {
        #pragma unroll
        for (int k = 0; k < CPT; ++k) s_wt[k][w] = s[k];   // wave totals
    }
    __syncthreads();

    // ---- Cross-wave suffix offsets + per-k grand totals (broadcast reads).
    float off[CPT], tot[CPT];
    #pragma unroll
    for (int k = 0; k < CPT; ++k) { off[k] = 0.f; tot[k] = 0.f; }
    #pragma unroll
    for (int w2 = 0; w2 < NW; ++w2) {
        #pragma unroll
        for (int k = 0; k < CPT; ++k) {
            const float tw = s_wt[k][w2];
            tot[k] += tw;
            if (w2 > w) off[k] += tw;
        }
    }
    // Exclusive suffix for chunk k of thread t: chunks >t within k, plus all of k' > k.
    float E[CPT];
    float higher = 0.f;
    #pragma unroll
    for (int k = CPT - 1; k >= 0; --k) {
        E[k] = (s[k] - v[k]) + off[k] + higher;
        higher += tot[k];
    }

    // ---- In-register reverse cumsum per chunk, nontemporal streaming stores.
    #pragma unroll
    for (int k = 0; k < CPT; ++k) {
        const int c = k * TPB + t;
        const float f[CHUNK] = {a[k].x, a[k].y, a[k].z, a[k].w,
                                b[k].x, b[k].y, b[k].z, b[k].w};
        float acc = E[k], o[CHUNK];
        #pragma unroll
        for (int j = CHUNK - 1; j >= 0; --j) { acc += f[j]; o[j] = acc; }
        f4 q0 = {o[0], o[1], o[2], o[3]};
        f4 q1 = {o[4], o[5], o[6], o[7]};
        __builtin_nontemporal_store(q0, outp4 + 2 * c);
        __builtin_nontemporal_store(q1, outp4 + 2 * c + 1);
    }
}

extern "C" void kernel_launch(void* const* d_in, const int* in_sizes, int n_in,
                              void* d_out, int out_size, void* d_ws, size_t ws_size,
                              hipStream_t stream) {
    const float* x = (const float*)d_in[0];
    float* out = (float*)d_out;
    const int rows = in_sizes[0] / COLS;   // 16384
    revcumsum_rows<<<rows, TPB, 0, stream>>>(x, out);
}

// Round 10
// 384.694 us; speedup vs baseline: 1.0566x; 1.0566x over previous
//
#include <hip/hip_runtime.h>

#define COLS 16384
#define TPB  1024
#define QPR  (COLS / 4)                           // 4096 quads per row
#define QPT  (QPR / TPB)                          // 4 quads per thread
#define NW   (TPB / 64)                           // 16 waves

typedef float f4 __attribute__((ext_vector_type(4)));

__global__ __launch_bounds__(TPB) void revcumsum_rows(const float* __restrict__ x,
                                                      float* __restrict__ out) {
    // Quad-granularity ownership: thread t owns quad k*TPB+t for k=0..3.
    // Every load/store is lane-contiguous 16B (1KB/wave-instr, copy-kernel pattern).
    __shared__ float s_wt[QPT][NW];                 // 256 B wave totals

    const int t    = threadIdx.x;
    const int lane = t & 63;
    const int w    = t >> 6;
    const long long row = blockIdx.x;
    const f4* __restrict__ rowp4 = reinterpret_cast<const f4*>(x + row * (long long)COLS);
    f4* __restrict__       outp4 = reinterpret_cast<f4*>(out + row * (long long)COLS);

    // ---- Load 4 quads nontemporally (fully coalesced), per-quad sums.
    f4 a[QPT];
    float v[QPT];
    #pragma unroll
    for (int k = 0; k < QPT; ++k) {
        a[k] = __builtin_nontemporal_load(rowp4 + k * TPB + t);
        v[k] = (a[k].x + a[k].y) + (a[k].z + a[k].w);
    }

    // ---- 4 wave-level inclusive SUFFIX scans over thread index.
    float s[QPT];
    #pragma unroll
    for (int k = 0; k < QPT; ++k) s[k] = v[k];
    #pragma unroll
    for (int d = 1; d < 64; d <<= 1) {
        float o[QPT];
        #pragma unroll
        for (int k = 0; k < QPT; ++k) o[k] = __shfl_down(s[k], d);
        if (lane + d < 64) {
            #pragma unroll
            for (int k = 0; k < QPT; ++k) s[k] += o[k];
        }
    }
    if (lane == 0) {
        #pragma unroll
        for (int k = 0; k < QPT; ++k) s_wt[k][w] = s[k];   // wave totals
    }
    __syncthreads();

    // ---- Cross-wave suffix offsets + per-segment grand totals (broadcast reads).
    float off[QPT], tot[QPT];
    #pragma unroll
    for (int k = 0; k < QPT; ++k) { off[k] = 0.f; tot[k] = 0.f; }
    #pragma unroll
    for (int w2 = 0; w2 < NW; ++w2) {
        #pragma unroll
        for (int k = 0; k < QPT; ++k) {
            const float tw = s_wt[k][w2];
            tot[k] += tw;
            if (w2 > w) off[k] += tw;
        }
    }
    // Exclusive suffix for quad (k,t): quads >t within segment k + all segments k'>k.
    float E[QPT];
    float higher = 0.f;
    #pragma unroll
    for (int k = QPT - 1; k >= 0; --k) {
        E[k] = (s[k] - v[k]) + off[k] + higher;
        higher += tot[k];
    }

    // ---- In-register reverse cumsum per quad, contiguous nontemporal stores.
    #pragma unroll
    for (int k = 0; k < QPT; ++k) {
        f4 q;
        float acc = E[k];
        acc += a[k].w; q.w = acc;
        acc += a[k].z; q.z = acc;
        acc += a[k].y; q.y = acc;
        acc += a[k].x; q.x = acc;
        __builtin_nontemporal_store(q, outp4 + k * TPB + t);
    }
}

extern "C" void kernel_launch(void* const* d_in, const int* in_sizes, int n_in,
                              void* d_out, int out_size, void* d_ws, size_t ws_size,
                              hipStream_t stream) {
    const float* x = (const float*)d_in[0];
    float* out = (float*)d_out;
    const int rows = in_sizes[0] / COLS;   // 16384
    revcumsum_rows<<<rows, TPB, 0, stream>>>(x, out);
}

// Round 11
// 373.304 us; speedup vs baseline: 1.0889x; 1.0305x over previous
//
#include <hip/hip_runtime.h>

#define COLS 16384
#define TPB  1024
#define CHUNK 8                                   // f32 elems per chunk
#define CPR  (COLS / CHUNK)                       // 2048 chunks per row
#define NW   (TPB / 64)                           // 16 waves

typedef float f4 __attribute__((ext_vector_type(4)));

__global__ __launch_bounds__(TPB) void revcumsum_rows(const float* __restrict__ x,
                                                      float* __restrict__ out) {
    // Register-resident row data; LDS = 2x16 wave totals only. One barrier.
    // Best of 7 structural variants (see session journal): 372.7us, 5.76 TB/s,
    // ~96% of the practical mixed read/write stream ceiling.
    __shared__ float s_wt0[NW];
    __shared__ float s_wt1[NW];

    const int t    = threadIdx.x;
    const int lane = t & 63;
    const int w    = t >> 6;
    const long long row = blockIdx.x;
    const f4* __restrict__ rowp4 = reinterpret_cast<const f4*>(x + row * (long long)COLS);
    f4* __restrict__       outp4 = reinterpret_cast<f4*>(out + row * (long long)COLS);

    // ---- Load both chunks (c0 = t, c1 = TPB + t) nontemporally into regs.
    const f4 a0 = __builtin_nontemporal_load(rowp4 + 2 * t);
    const f4 b0 = __builtin_nontemporal_load(rowp4 + 2 * t + 1);
    const f4 a1 = __builtin_nontemporal_load(rowp4 + 2 * (TPB + t));
    const f4 b1 = __builtin_nontemporal_load(rowp4 + 2 * (TPB + t) + 1);

    // Per-chunk fp32 sums (no LDS needed — data is ours).
    const float v0 = ((a0.x + a0.y) + (a0.z + a0.w)) + ((b0.x + b0.y) + (b0.z + b0.w));
    const float v1 = ((a1.x + a1.y) + (a1.z + a1.w)) + ((b1.x + b1.y) + (b1.z + b1.w));

    // ---- Paired wave-level inclusive SUFFIX scan over thread index.
    float s0 = v0, s1 = v1;
    #pragma unroll
    for (int d = 1; d < 64; d <<= 1) {
        const float o0 = __shfl_down(s0, d);
        const float o1 = __shfl_down(s1, d);
        if (lane + d < 64) { s0 += o0; s1 += o1; }
    }
    if (lane == 0) { s_wt0[w] = s0; s_wt1[w] = s1; }   // wave totals
    __syncthreads();

    // Cross-wave suffix offsets + grand total of the k=1 half.
    float off0 = 0.f, off1 = 0.f, total1 = 0.f;
    #pragma unroll
    for (int w2 = 0; w2 < NW; ++w2) {
        const float t1 = s_wt1[w2];                    // broadcast reads
        total1 += t1;
        if (w2 > w) { off0 += s_wt0[w2]; off1 += t1; }
    }
    // Exclusive suffixes: chunk t sees all chunks >t in k=0 plus ALL of k=1.
    const float E0 = (s0 - v0) + off0 + total1;
    const float E1 = (s1 - v1) + off1;

    // ---- In-register reverse cumsum per chunk, nontemporal streaming stores.
    {
        const float f[CHUNK] = {a0.x, a0.y, a0.z, a0.w, b0.x, b0.y, b0.z, b0.w};
        float acc = E0, o[CHUNK];
        #pragma unroll
        for (int j = CHUNK - 1; j >= 0; --j) { acc += f[j]; o[j] = acc; }
        f4 q0 = {o[0], o[1], o[2], o[3]};
        f4 q1 = {o[4], o[5], o[6], o[7]};
        __builtin_nontemporal_store(q0, outp4 + 2 * t);
        __builtin_nontemporal_store(q1, outp4 + 2 * t + 1);
    }
    {
        const float f[CHUNK] = {a1.x, a1.y, a1.z, a1.w, b1.x, b1.y, b1.z, b1.w};
        float acc = E1, o[CHUNK];
        #pragma unroll
        for (int j = CHUNK - 1; j >= 0; --j) { acc += f[j]; o[j] = acc; }
        f4 q0 = {o[0], o[1], o[2], o[3]};
        f4 q1 = {o[4], o[5], o[6], o[7]};
        __builtin_nontemporal_store(q0, outp4 + 2 * (TPB + t));
        __builtin_nontemporal_store(q1, outp4 + 2 * (TPB + t) + 1);
    }
}

extern "C" void kernel_launch(void* const* d_in, const int* in_sizes, int n_in,
                              void* d_out, int out_size, void* d_ws, size_t ws_size,
                              hipStream_t stream) {
    const float* x = (const float*)d_in[0];
    float* out = (float*)d_out;
    const int rows = in_sizes[0] / COLS;   // 16384
    revcumsum_rows<<<rows, TPB, 0, stream>>>(x, out);
}